// Round 13
// baseline (128.323 us; speedup 1.0000x reference)
//
#include <hip/hip_runtime.h>

// BitConv2d: x (16,32,224,224) f32, w (32,32,3,3) f32, out (16,32,224,224) f32.
// out = conv(x_q, w_q) * (x_scale/127 * w_scale); x_q in [-128,127], w_q in {-1,0,1}.
// Both exact in bf16 -> bf16 MFMA computes the integer conv exactly (|sum| < 2^24).
//
// 2 dispatches:
//  absmax: 2049 blocks (weight-quant block at idx 0, overlapped; 2048 x-slices)
//  conv:   784 persistent blocks (all co-resident at 4 blocks/CU), each does 4
//          vertically-adjacent 8x32 tiles with issue-early x prefetch across
//          tiles (T14) and weights staged in LDS (MFMA phase is vmem-free).

typedef __attribute__((ext_vector_type(8))) short short8;
typedef __attribute__((ext_vector_type(4))) float f32x4;

#define HW    224
#define NCH   32
#define PLANE (HW * HW)   // 50176
#define TH 8
#define TW 32
#define NX4   (16 * NCH * PLANE / 4)
// LDS: xs = 340 px (10 rows x 34 cols) x 32 ch bf16 = 21760 B (granule-XOR swizzled)
//      wl = 18 frags x 512 bf16 = 18432 B ; total 40.2 KB -> 4 blocks/CU

__device__ __forceinline__ int lds_h(int pix, int c) {
    int sw = (pix & 3) ^ ((pix >> 2) & 3);
    return pix * 32 + (c & 7) + ((((c >> 3) ^ sw) & 3) << 3);
}

__device__ __forceinline__ unsigned short q8(float v) {
    float q = rintf(fminf(127.f, fmaxf(-128.f, v)));   // round-half-even like jnp.round
    return (unsigned short)(__float_as_uint(q) >> 16); // exact bf16 of small ints
}

// ws layout: [0, 8192) = u32 slots[2048] (fully rewritten each call);
// 8192: scal[0] = wscale; 8448: wbuf 18 frags x 512 bf16.
// frag (tap*2+kb): lane l elem j = w_q[kout = kb*16+(l&15)][c = (l>>4)*8+j][tap/3][tap%3]

__global__ __launch_bounds__(256) void absmax_kernel(const float* __restrict__ x,
                                                     const float* __restrict__ w,
                                                     unsigned* __restrict__ slots,
                                                     float* __restrict__ scal,
                                                     unsigned short* __restrict__ wbuf)
{
    int tid = threadIdx.x;
    int lane = tid & 63, wv = tid >> 6;

    if (blockIdx.x == 0) {
        // ---- weight block (first: overlaps the x-pass) ----
        float s = 0.f;
        for (int i = tid; i < 9216; i += 256) s += fabsf(w[i]);
        #pragma unroll
        for (int off = 32; off > 0; off >>= 1) s += __shfl_xor(s, off);
        __shared__ float sm[4];
        __shared__ float s_ws;
        if (lane == 0) sm[wv] = s;
        __syncthreads();
        if (tid == 0) {
            float wscale = (sm[0] + sm[1] + sm[2] + sm[3]) / 9216.f + 1e-5f;
            scal[0] = wscale;
            s_ws = wscale;
        }
        __syncthreads();
        float wscale = s_ws;
        for (int o = tid; o < 9216; o += 256) {
            int frag = o >> 9, rem = o & 511;
            int l = rem >> 3, j = rem & 7;
            int tap = frag >> 1, kb = frag & 1;
            int kout = kb * 16 + (l & 15);
            int c = ((l >> 4) << 3) + j;
            int r = tap / 3, ss = tap % 3;
            float wv2 = w[((kout * 32 + c) * 3 + r) * 3 + ss];
            float q = fminf(1.f, fmaxf(-1.f, rintf(wv2 / wscale)));
            wbuf[o] = (unsigned short)(__float_as_uint(q) >> 16);   // exact bf16
        }
        return;
    }

    // ---- x-slice absmax ----
    const float4* x4 = (const float4*)x;
    float m = 0.f;
    for (int i = (blockIdx.x - 1) * 256 + tid; i < NX4; i += 2048 * 256) {
        float4 v = x4[i];
        m = fmaxf(m, fmaxf(fmaxf(fabsf(v.x), fabsf(v.y)),
                           fmaxf(fabsf(v.z), fabsf(v.w))));
    }
    #pragma unroll
    for (int off = 32; off > 0; off >>= 1)
        m = fmaxf(m, __shfl_xor(m, off));
    __shared__ float wm[4];
    if (lane == 0) wm[wv] = m;
    __syncthreads();
    if (tid == 0) {
        m = fmaxf(fmaxf(wm[0], wm[1]), fmaxf(wm[2], wm[3]));
        slots[blockIdx.x - 1] = __float_as_uint(m);   // plain store, no atomics
    }
}

__global__ __launch_bounds__(256, 4) void conv_kernel(const float* __restrict__ x,
                                                      const unsigned short* __restrict__ wbuf,
                                                      const unsigned* __restrict__ slots,
                                                      const float* __restrict__ scal,
                                                      float* __restrict__ out)
{
    __shared__ __align__(16) unsigned short xs[340 * 32];   // 21760 B
    __shared__ __align__(16) unsigned short wl[18 * 512];   // 18432 B
    __shared__ float sred[4];

    // bijective XCD swizzle: 784 blocks = 8 XCDs x 98 contiguous (= 2 images each)
    int bid = (blockIdx.x & 7) * 98 + (blockIdx.x >> 3);
    int tw = bid % 7;
    int rest = bid / 7;
    int qh = rest % 7;
    int n  = rest / 7;
    int w0 = tw * TW;
    int hb = qh * 32;                 // 4 tiles: rows hb .. hb+31

    int tid = threadIdx.x;
    int lane = tid & 63, wv = tid >> 6;   // wv in 0..3

    const float* xn = x + n * (NCH * PLANE);
    float* on = out + n * (NCH * PLANE);

    // staging map: slot = tid&7 (4-px col group), c = tid>>3 (channel 0..31)
    int slot = tid & 7;
    int c = tid >> 3;
    const float* tb = xn + c * PLANE + w0 + slot * 4;
    int pixb = 1 + slot * 4;

    // ---- issue order: slots, weights->LDS, then tile-0 x loads ----
    uint4 s0 = ((const uint4*)slots)[tid];
    uint4 s1 = ((const uint4*)slots)[tid + 256];
    float wscale = scal[0];

    const short8* wfp = (const short8*)wbuf;
    short8* wl8 = (short8*)wl;
    #pragma unroll
    for (int i = 0; i < 5; ++i) {
        int idx = tid + i * 256;
        if (idx < 1152) wl8[idx] = wfp[idx];   // 18 KB, one-time
    }

    float4 va[5], vb[5];
    float hv[3];
    {
        int h0 = hb;
        #pragma unroll
        for (int i = 0; i < 5; ++i) {
            int gh = h0 - 1 + i;
            int ghc = gh < 0 ? 0 : gh;
            va[i] = *(const float4*)(tb + ghc * HW);
        }
        #pragma unroll
        for (int i = 0; i < 5; ++i) {
            int gh = h0 + 4 + i;
            vb[i] = *(const float4*)(tb + gh * HW);
        }
        #pragma unroll
        for (int it = 0; it < 3; ++it) {
            int e = tid + it * 256;
            hv[it] = 0.f;
            if (e < 640) {
                int side = e & 1, cc = (e >> 1) & 31, hp = e >> 6;
                int gh = h0 - 1 + hp;
                int gw = side ? (w0 + TW) : (w0 - 1);
                int ghc = gh < 0 ? 0 : gh;
                int gwc = gw < 0 ? 0 : (gw > HW - 1 ? HW - 1 : gw);
                hv[it] = xn[cc * PLANE + ghc * HW + gwc];
            }
        }
    }

    // ---- xmax reduce (x loads + weight staging in flight) ----
    float m2 = fmaxf(fmaxf(fmaxf(__uint_as_float(s0.x), __uint_as_float(s0.y)),
                           fmaxf(__uint_as_float(s0.z), __uint_as_float(s0.w))),
                     fmaxf(fmaxf(__uint_as_float(s1.x), __uint_as_float(s1.y)),
                           fmaxf(__uint_as_float(s1.z), __uint_as_float(s1.w))));
    #pragma unroll
    for (int off = 32; off > 0; off >>= 1)
        m2 = fmaxf(m2, __shfl_xor(m2, off));
    if (lane == 0) sred[wv] = m2;
    __syncthreads();
    float xmax = fmaxf(fmaxf(sred[0], sred[1]), fmaxf(sred[2], sred[3]));
    float xscale = xmax + 1e-5f;
    float inv = 127.f / xscale;
    float osc = (xscale / 127.f) * wscale;

    int ln = lane & 15, cb = lane >> 4;

    for (int t = 0; t < 4; ++t) {
        int h0 = hb + t * TH;

        // ---- quantize + LDS write tile t (loads already in flight) ----
        #pragma unroll
        for (int i = 0; i < 5; ++i) {
            int gh = h0 - 1 + i;
            float vs = ((unsigned)gh < (unsigned)HW) ? inv : 0.f;
            int p0 = i * 34 + pixb;
            xs[lds_h(p0 + 0, c)] = q8(va[i].x * vs);
            xs[lds_h(p0 + 1, c)] = q8(va[i].y * vs);
            xs[lds_h(p0 + 2, c)] = q8(va[i].z * vs);
            xs[lds_h(p0 + 3, c)] = q8(va[i].w * vs);
        }
        #pragma unroll
        for (int it = 0; it < 3; ++it) {
            int e = tid + it * 256;
            if (e < 640) {
                int side = e & 1, cc = (e >> 1) & 31, hp = e >> 6;
                int gh = h0 - 1 + hp;
                int gw = side ? (w0 + TW) : (w0 - 1);
                float vs = ((unsigned)gh < (unsigned)HW && (unsigned)gw < (unsigned)HW)
                               ? inv : 0.f;
                xs[lds_h(hp * 34 + (side ? 33 : 0), cc)] = q8(hv[it] * vs);
            }
        }
        #pragma unroll
        for (int i = 0; i < 5; ++i) {
            int gh = h0 + 4 + i;
            float vs = (gh < HW) ? inv : 0.f;
            int p0 = (5 + i) * 34 + pixb;
            xs[lds_h(p0 + 0, c)] = q8(vb[i].x * vs);
            xs[lds_h(p0 + 1, c)] = q8(vb[i].y * vs);
            xs[lds_h(p0 + 2, c)] = q8(vb[i].z * vs);
            xs[lds_h(p0 + 3, c)] = q8(vb[i].w * vs);
        }
        __syncthreads();   // xs(t) + (t==0) weights visible

        // ---- issue tile t+1 x loads: HBM latency hides under MFMA + epilogue ----
        if (t < 3) {
            int h1 = h0 + TH;
            #pragma unroll
            for (int i = 0; i < 5; ++i) {
                int gh = h1 - 1 + i;
                va[i] = *(const float4*)(tb + gh * HW);
            }
            #pragma unroll
            for (int i = 0; i < 5; ++i) {
                int gh = h1 + 4 + i;
                int ghc = gh > HW - 1 ? HW - 1 : gh;
                vb[i] = *(const float4*)(tb + ghc * HW);
            }
            #pragma unroll
            for (int it = 0; it < 3; ++it) {
                int e = tid + it * 256;
                if (e < 640) {
                    int side = e & 1, cc = (e >> 1) & 31, hp = e >> 6;
                    int gh = h1 - 1 + hp;
                    int gw = side ? (w0 + TW) : (w0 - 1);
                    int ghc = gh > HW - 1 ? HW - 1 : gh;
                    int gwc = gw < 0 ? 0 : (gw > HW - 1 ? HW - 1 : gw);
                    hv[it] = xn[cc * PLANE + ghc * HW + gwc];
                }
            }
        }

        // ---- MFMA: vmem-free (weights from LDS), 9 taps x [2 ri][2 pb][2 kb] ----
        f32x4 acc[2][2][2] = {};
        #pragma unroll
        for (int tap = 0; tap < 9; ++tap) {
            short8 wa = wl8[(2 * tap) * 64 + lane];
            short8 wb = wl8[(2 * tap + 1) * 64 + lane];
            int r = tap / 3;
            int s2 = tap - r * 3;
            #pragma unroll
            for (int ri = 0; ri < 2; ++ri) {
                #pragma unroll
                for (int pb = 0; pb < 2; ++pb) {
                    int pix = (wv * 2 + ri + r) * 34 + pb * 16 + ln + s2;
                    int sw = (pix & 3) ^ ((pix >> 2) & 3);
                    const short8 a = *(const short8*)&xs[pix * 32 + (((cb ^ sw) & 3) << 3)];
                    acc[ri][pb][0] = __builtin_amdgcn_mfma_f32_16x16x32_bf16(
                        a, wa, acc[ri][pb][0], 0, 0, 0);
                    acc[ri][pb][1] = __builtin_amdgcn_mfma_f32_16x16x32_bf16(
                        a, wb, acc[ri][pb][1], 0, 0, 0);
                }
            }
        }

        // ---- epilogue: D row = pixel -> lane holds 4 consecutive px ----
        #pragma unroll
        for (int ri = 0; ri < 2; ++ri) {
            int h = h0 + wv * 2 + ri;
            #pragma unroll
            for (int pb = 0; pb < 2; ++pb) {
                int wcol = w0 + pb * 16 + cb * 4;
                #pragma unroll
                for (int kb = 0; kb < 2; ++kb) {
                    int k = kb * 16 + ln;
                    f32x4 o;
                    o[0] = acc[ri][pb][kb][0] * osc;
                    o[1] = acc[ri][pb][kb][1] * osc;
                    o[2] = acc[ri][pb][kb][2] * osc;
                    o[3] = acc[ri][pb][kb][3] * osc;
                    *(f32x4*)&on[(k * HW + h) * HW + wcol] = o;
                }
            }
        }
        __syncthreads();   // all xs(t) reads done before next quant overwrites
    }
}

extern "C" void kernel_launch(void* const* d_in, const int* in_sizes, int n_in,
                              void* d_out, int out_size, void* d_ws, size_t ws_size,
                              hipStream_t stream)
{
    const float* x = (const float*)d_in[0];
    const float* w = (const float*)d_in[1];
    float* outp = (float*)d_out;
    unsigned* slots = (unsigned*)d_ws;
    float* scal = (float*)((char*)d_ws + 8192);
    unsigned short* wbuf = (unsigned short*)((char*)d_ws + 8448);

    absmax_kernel<<<2049, 256, 0, stream>>>(x, w, slots, scal, wbuf);
    conv_kernel<<<16 * 7 * 7, 256, 0, stream>>>(x, wbuf, slots, scal, outp);
}

// Round 14
// 83.728 us; speedup vs baseline: 1.5326x; 1.5326x over previous
//
#include <hip/hip_runtime.h>

// BitConv2d: x (16,32,224,224) f32, w (32,32,3,3) f32, out (16,32,224,224) f32.
// out = conv(x_q, w_q) * (x_scale/127 * w_scale); x_q in [-128,127], w_q in {-1,0,1}.
// Both exact in bf16 -> bf16 MFMA computes the integer conv exactly (|sum| < 2^24).
//
// 2 dispatches: absmax (2049 blocks: weight block first, 2048 x-slices),
// conv (3136 blocks x one 8x32 tile, 256 thr, minimal-liveness interleaved
// staging, no launch-bounds clamp -> compiler-natural VGPR, ~6 blocks/CU TLP).

typedef __attribute__((ext_vector_type(8))) short short8;
typedef __attribute__((ext_vector_type(4))) float f32x4;

#define HW    224
#define NCH   32
#define PLANE (HW * HW)   // 50176
#define TH 8
#define TW 32
#define NX4   (16 * NCH * PLANE / 4)
// LDS tile: 340 pixels (10 rows x 34 cols) x 32 ch bf16 = 21760 B, granule-XOR swizzled.

__device__ __forceinline__ int lds_h(int pix, int c) {
    int sw = (pix & 3) ^ ((pix >> 2) & 3);
    return pix * 32 + (c & 7) + ((((c >> 3) ^ sw) & 3) << 3);
}

__device__ __forceinline__ unsigned short q8(float v) {
    float q = rintf(fminf(127.f, fmaxf(-128.f, v)));   // round-half-even like jnp.round
    return (unsigned short)(__float_as_uint(q) >> 16); // exact bf16 of small ints
}

// ws layout: [0, 8192) = u32 slots[2048] (fully rewritten each call);
// 8192: scal[0] = wscale; 8448: wbuf 18 frags x 512 bf16.
// frag (tap*2+kb): lane l elem j = w_q[kout = kb*16+(l&15)][c = (l>>4)*8+j][tap/3][tap%3]

__global__ __launch_bounds__(256) void absmax_kernel(const float* __restrict__ x,
                                                     const float* __restrict__ w,
                                                     unsigned* __restrict__ slots,
                                                     float* __restrict__ scal,
                                                     unsigned short* __restrict__ wbuf)
{
    int tid = threadIdx.x;
    int lane = tid & 63, wv = tid >> 6;

    if (blockIdx.x == 0) {
        // ---- weight block (first: overlaps the x-pass) ----
        float s = 0.f;
        for (int i = tid; i < 9216; i += 256) s += fabsf(w[i]);
        #pragma unroll
        for (int off = 32; off > 0; off >>= 1) s += __shfl_xor(s, off);
        __shared__ float sm[4];
        __shared__ float s_ws;
        if (lane == 0) sm[wv] = s;
        __syncthreads();
        if (tid == 0) {
            float wscale = (sm[0] + sm[1] + sm[2] + sm[3]) / 9216.f + 1e-5f;
            scal[0] = wscale;
            s_ws = wscale;
        }
        __syncthreads();
        float wscale = s_ws;
        for (int o = tid; o < 9216; o += 256) {
            int frag = o >> 9, rem = o & 511;
            int l = rem >> 3, j = rem & 7;
            int tap = frag >> 1, kb = frag & 1;
            int kout = kb * 16 + (l & 15);
            int c = ((l >> 4) << 3) + j;
            int r = tap / 3, ss = tap % 3;
            float wv2 = w[((kout * 32 + c) * 3 + r) * 3 + ss];
            float q = fminf(1.f, fmaxf(-1.f, rintf(wv2 / wscale)));
            wbuf[o] = (unsigned short)(__float_as_uint(q) >> 16);   // exact bf16
        }
        return;
    }

    // ---- x-slice absmax ----
    const float4* x4 = (const float4*)x;
    float m = 0.f;
    for (int i = (blockIdx.x - 1) * 256 + tid; i < NX4; i += 2048 * 256) {
        float4 v = x4[i];
        m = fmaxf(m, fmaxf(fmaxf(fabsf(v.x), fabsf(v.y)),
                           fmaxf(fabsf(v.z), fabsf(v.w))));
    }
    #pragma unroll
    for (int off = 32; off > 0; off >>= 1)
        m = fmaxf(m, __shfl_xor(m, off));
    __shared__ float wm[4];
    if (lane == 0) wm[wv] = m;
    __syncthreads();
    if (tid == 0) {
        m = fmaxf(fmaxf(wm[0], wm[1]), fmaxf(wm[2], wm[3]));
        slots[blockIdx.x - 1] = __float_as_uint(m);   // plain store, no atomics
    }
}

__global__ __launch_bounds__(256) void conv_kernel(const float* __restrict__ x,
                                                   const unsigned short* __restrict__ wbuf,
                                                   const unsigned* __restrict__ slots,
                                                   const float* __restrict__ scal,
                                                   float* __restrict__ out)
{
    __shared__ __align__(16) unsigned short xs[340 * 32];   // 21760 B
    __shared__ float sred[4];

    // bijective XCD swizzle: 3136 blocks = 8 XCDs x 392 contiguous (= 2 images each)
    int bid = (blockIdx.x & 7) * 392 + (blockIdx.x >> 3);
    int tw = bid % 7;
    int rest = bid / 7;
    int th = rest % 28;
    int n  = rest / 28;
    int h0 = th * TH, w0 = tw * TW;

    int tid = threadIdx.x;
    int lane = tid & 63, wv = tid >> 6;   // wv in 0..3

    const float* xn = x + n * (NCH * PLANE);

    // ---- xmax from the 2048 slots (first; everything else depends on it) ----
    uint4 s0 = ((const uint4*)slots)[tid];
    uint4 s1 = ((const uint4*)slots)[tid + 256];
    float wscale = scal[0];
    float m2 = fmaxf(fmaxf(fmaxf(__uint_as_float(s0.x), __uint_as_float(s0.y)),
                           fmaxf(__uint_as_float(s0.z), __uint_as_float(s0.w))),
                     fmaxf(fmaxf(__uint_as_float(s1.x), __uint_as_float(s1.y)),
                           fmaxf(__uint_as_float(s1.z), __uint_as_float(s1.w))));
    #pragma unroll
    for (int off = 32; off > 0; off >>= 1)
        m2 = fmaxf(m2, __shfl_xor(m2, off));
    if (lane == 0) sred[wv] = m2;
    __syncthreads();
    float xmax = fmaxf(fmaxf(sred[0], sred[1]), fmaxf(sred[2], sred[3]));
    float xscale = xmax + 1e-5f;
    float inv = 127.f / xscale;
    float osc = (xscale / 127.f) * wscale;

    // ---- interleaved staging (minimal liveness): 10 rows, load->quant->write ----
    {
        int slot = tid & 7;
        int c = tid >> 3;
        const float* tb = xn + c * PLANE + w0 + slot * 4;
        int pixb = 1 + slot * 4;
        #pragma unroll 2
        for (int hp = 0; hp < 10; ++hp) {
            int gh = h0 - 1 + hp;
            int ghc = gh < 0 ? 0 : (gh > HW - 1 ? HW - 1 : gh);
            float4 v = *(const float4*)(tb + ghc * HW);
            float vs = (gh == ghc) ? inv : 0.f;
            int p0 = hp * 34 + pixb;
            xs[lds_h(p0 + 0, c)] = q8(v.x * vs);
            xs[lds_h(p0 + 1, c)] = q8(v.y * vs);
            xs[lds_h(p0 + 2, c)] = q8(v.z * vs);
            xs[lds_h(p0 + 3, c)] = q8(v.w * vs);
        }
    }
    // halo cols wp=0 / wp=33: 10 rows x 32 ch x 2 = 640 elements, interleaved
    #pragma unroll
    for (int it = 0; it < 3; ++it) {
        int e = tid + it * 256;
        if (e < 640) {
            int side = e & 1, cc = (e >> 1) & 31, hp = e >> 6;
            int gh = h0 - 1 + hp;
            int gw = side ? (w0 + TW) : (w0 - 1);
            int ghc = gh < 0 ? 0 : (gh > HW - 1 ? HW - 1 : gh);
            int gwc = gw < 0 ? 0 : (gw > HW - 1 ? HW - 1 : gw);
            float v = xn[cc * PLANE + ghc * HW + gwc];
            float vs = (gh == ghc && gw == gwc) ? inv : 0.f;
            xs[lds_h(hp * 34 + (side ? 33 : 0), cc)] = q8(v * vs);
        }
    }
    __syncthreads();

    // ---- MFMA: 9 taps x [2 ri][2 pb][2 kb], one-ahead weight prefetch ----
    int ln = lane & 15, cb = lane >> 4;
    f32x4 acc[2][2][2] = {};
    const short8* wfp = (const short8*)wbuf;
    short8 wa = wfp[lane];
    short8 wb = wfp[64 + lane];
    for (int tap = 0; tap < 9; ++tap) {
        short8 na, nb;
        if (tap < 8) {
            na = wfp[(2 * tap + 2) * 64 + lane];
            nb = wfp[(2 * tap + 3) * 64 + lane];
        }
        int r = tap / 3;
        int s2 = tap - r * 3;
        #pragma unroll
        for (int ri = 0; ri < 2; ++ri) {
            #pragma unroll
            for (int pb = 0; pb < 2; ++pb) {
                int pix = (wv * 2 + ri + r) * 34 + pb * 16 + ln + s2;
                int sw = (pix & 3) ^ ((pix >> 2) & 3);
                const short8 a = *(const short8*)&xs[pix * 32 + (((cb ^ sw) & 3) << 3)];
                acc[ri][pb][0] = __builtin_amdgcn_mfma_f32_16x16x32_bf16(
                    a, wa, acc[ri][pb][0], 0, 0, 0);
                acc[ri][pb][1] = __builtin_amdgcn_mfma_f32_16x16x32_bf16(
                    a, wb, acc[ri][pb][1], 0, 0, 0);
            }
        }
        wa = na;
        wb = nb;
    }

    // ---- epilogue: D row = pixel -> lane holds 4 consecutive px: float4 stores ----
    float* on = out + n * (NCH * PLANE);
    #pragma unroll
    for (int ri = 0; ri < 2; ++ri) {
        int h = h0 + wv * 2 + ri;
        #pragma unroll
        for (int pb = 0; pb < 2; ++pb) {
            int wcol = w0 + pb * 16 + cb * 4;
            #pragma unroll
            for (int kb = 0; kb < 2; ++kb) {
                int k = kb * 16 + ln;
                f32x4 o;
                o[0] = acc[ri][pb][kb][0] * osc;
                o[1] = acc[ri][pb][kb][1] * osc;
                o[2] = acc[ri][pb][kb][2] * osc;
                o[3] = acc[ri][pb][kb][3] * osc;
                *(f32x4*)&on[(k * HW + h) * HW + wcol] = o;
            }
        }
    }
}

extern "C" void kernel_launch(void* const* d_in, const int* in_sizes, int n_in,
                              void* d_out, int out_size, void* d_ws, size_t ws_size,
                              hipStream_t stream)
{
    const float* x = (const float*)d_in[0];
    const float* w = (const float*)d_in[1];
    float* outp = (float*)d_out;
    unsigned* slots = (unsigned*)d_ws;
    float* scal = (float*)((char*)d_ws + 8192);
    unsigned short* wbuf = (unsigned short*)((char*)d_ws + 8448);

    absmax_kernel<<<2049, 256, 0, stream>>>(x, w, slots, scal, wbuf);
    conv_kernel<<<16 * 28 * 7, 256, 0, stream>>>(x, wbuf, slots, scal, outp);
}

// Round 15
// 72.809 us; speedup vs baseline: 1.7625x; 1.1500x over previous
//
#include <hip/hip_runtime.h>

// BitConv2d: x (16,32,224,224) f32, w (32,32,3,3) f32, out (16,32,224,224) f32.
// out = conv(x_q, w_q) * (x_scale/127 * w_scale); x_q in [-128,127], w_q in {-1,0,1}.
// Both exact in bf16 -> bf16 MFMA computes the integer conv exactly (|sum| < 2^24).
//
// 2 dispatches:
//  absmax: 2048 blocks EXACTLY (8/CU perfect fill): block 0 = weight quant only,
//          blocks 1..2047 = x absmax over 2047 contiguous-ish strided slices.
//  conv:   3136 blocks x one 8x32 tile, 256 thr, (256,5) => VGPR<=64 (batched
//          issue-early staging live set ~61 fits), 7 blocks/CU via 21.76KB LDS.

typedef __attribute__((ext_vector_type(8))) short short8;
typedef __attribute__((ext_vector_type(4))) float f32x4;

#define HW    224
#define NCH   32
#define PLANE (HW * HW)   // 50176
#define TH 8
#define TW 32
#define NX4   (16 * NCH * PLANE / 4)
// LDS tile: 340 pixels (10 rows x 34 cols) x 32 ch bf16 = 21760 B, granule-XOR swizzled.

__device__ __forceinline__ int lds_h(int pix, int c) {
    int sw = (pix & 3) ^ ((pix >> 2) & 3);
    return pix * 32 + (c & 7) + ((((c >> 3) ^ sw) & 3) << 3);
}

__device__ __forceinline__ unsigned short q8(float v) {
    float q = rintf(fminf(127.f, fmaxf(-128.f, v)));   // round-half-even like jnp.round
    return (unsigned short)(__float_as_uint(q) >> 16); // exact bf16 of small ints
}

// ws layout: [0, 8192) = u32 slots[2048] (slot 0 unused-but-written; fully
// rewritten each call); 8192: scal[0] = wscale; 8448: wbuf 18 frags x 512 bf16.
// frag (tap*2+kb): lane l elem j = w_q[kout = kb*16+(l&15)][c = (l>>4)*8+j][tap/3][tap%3]

__global__ __launch_bounds__(256) void absmax_kernel(const float* __restrict__ x,
                                                     const float* __restrict__ w,
                                                     unsigned* __restrict__ slots,
                                                     float* __restrict__ scal,
                                                     unsigned short* __restrict__ wbuf)
{
    int tid = threadIdx.x;
    int lane = tid & 63, wv = tid >> 6;

    if (blockIdx.x == 0) {
        // ---- weight-only block (first block of a perfectly-filled grid) ----
        float s = 0.f;
        for (int i = tid; i < 9216; i += 256) s += fabsf(w[i]);
        #pragma unroll
        for (int off = 32; off > 0; off >>= 1) s += __shfl_xor(s, off);
        __shared__ float sm[4];
        __shared__ float s_ws;
        if (lane == 0) sm[wv] = s;
        __syncthreads();
        if (tid == 0) {
            float wscale = (sm[0] + sm[1] + sm[2] + sm[3]) / 9216.f + 1e-5f;
            scal[0] = wscale;
            s_ws = wscale;
            slots[0] = 0u;                     // keep slot array fully defined
        }
        __syncthreads();
        float wscale = s_ws;
        for (int o = tid; o < 9216; o += 256) {
            int frag = o >> 9, rem = o & 511;
            int l = rem >> 3, j = rem & 7;
            int tap = frag >> 1, kb = frag & 1;
            int kout = kb * 16 + (l & 15);
            int c = ((l >> 4) << 3) + j;
            int r = tap / 3, ss = tap % 3;
            float wv2 = w[((kout * 32 + c) * 3 + r) * 3 + ss];
            float q = fminf(1.f, fmaxf(-1.f, rintf(wv2 / wscale)));
            wbuf[o] = (unsigned short)(__float_as_uint(q) >> 16);   // exact bf16
        }
        return;
    }

    // ---- x-slice absmax: 2047 blocks grid-stride the whole array ----
    const float4* x4 = (const float4*)x;
    float m = 0.f;
    for (int i = (blockIdx.x - 1) * 256 + tid; i < NX4; i += 2047 * 256) {
        float4 v = x4[i];
        m = fmaxf(m, fmaxf(fmaxf(fabsf(v.x), fabsf(v.y)),
                           fmaxf(fabsf(v.z), fabsf(v.w))));
    }
    #pragma unroll
    for (int off = 32; off > 0; off >>= 1)
        m = fmaxf(m, __shfl_xor(m, off));
    __shared__ float wm[4];
    if (lane == 0) wm[wv] = m;
    __syncthreads();
    if (tid == 0) {
        m = fmaxf(fmaxf(wm[0], wm[1]), fmaxf(wm[2], wm[3]));
        slots[blockIdx.x] = __float_as_uint(m);   // plain store, no atomics
    }
}

__global__ __launch_bounds__(256, 5) void conv_kernel(const float* __restrict__ x,
                                                      const unsigned short* __restrict__ wbuf,
                                                      const unsigned* __restrict__ slots,
                                                      const float* __restrict__ scal,
                                                      float* __restrict__ out)
{
    __shared__ __align__(16) unsigned short xs[340 * 32];   // 21760 B
    __shared__ float sred[4];

    // bijective XCD swizzle: 3136 blocks = 8 XCDs x 392 contiguous (= 2 images each)
    int bid = (blockIdx.x & 7) * 392 + (blockIdx.x >> 3);
    int tw = bid % 7;
    int rest = bid / 7;
    int th = rest % 28;
    int n  = rest / 28;
    int h0 = th * TH, w0 = tw * TW;

    int tid = threadIdx.x;
    int lane = tid & 63, wv = tid >> 6;   // wv in 0..3

    const float* xn = x + n * (NCH * PLANE);

    // staging map: slot = tid&7 (4-px col group), c = tid>>3 (channel 0..31)
    int slot = tid & 7;
    int c = tid >> 3;
    const float* tb = xn + c * PLANE + w0 + slot * 4;
    int pixb = 1 + slot * 4;

    // ---- issue order: slots first (reduce drains only these), then all x loads ----
    uint4 s0 = ((const uint4*)slots)[tid];
    uint4 s1 = ((const uint4*)slots)[tid + 256];
    float wscale = scal[0];

    float hv[3];
    #pragma unroll
    for (int it = 0; it < 3; ++it) {
        int e = tid + it * 256;
        hv[it] = 0.f;
        if (e < 640) {      // halo cols: 10 rows x 32 ch x 2 sides
            int side = e & 1, cc = (e >> 1) & 31, hp = e >> 6;
            int gh = h0 - 1 + hp;
            int gw = side ? (w0 + TW) : (w0 - 1);
            int ghc = gh < 0 ? 0 : (gh > HW - 1 ? HW - 1 : gh);
            int gwc = gw < 0 ? 0 : (gw > HW - 1 ? HW - 1 : gw);
            hv[it] = xn[cc * PLANE + ghc * HW + gwc];
        }
    }
    float4 va[5], vb[5];
    #pragma unroll
    for (int i = 0; i < 5; ++i) {
        int gh = h0 - 1 + i;
        int ghc = gh < 0 ? 0 : (gh > HW - 1 ? HW - 1 : gh);
        va[i] = *(const float4*)(tb + ghc * HW);
    }
    #pragma unroll
    for (int i = 0; i < 5; ++i) {
        int gh = h0 + 4 + i;              // rows 5..9: gh = h0-1+5+i
        int ghc = gh > HW - 1 ? HW - 1 : gh;
        vb[i] = *(const float4*)(tb + ghc * HW);
    }

    // ---- xmax reduce (x loads still in flight) ----
    float m2 = fmaxf(fmaxf(fmaxf(__uint_as_float(s0.x), __uint_as_float(s0.y)),
                           fmaxf(__uint_as_float(s0.z), __uint_as_float(s0.w))),
                     fmaxf(fmaxf(__uint_as_float(s1.x), __uint_as_float(s1.y)),
                           fmaxf(__uint_as_float(s1.z), __uint_as_float(s1.w))));
    #pragma unroll
    for (int off = 32; off > 0; off >>= 1)
        m2 = fmaxf(m2, __shfl_xor(m2, off));
    if (lane == 0) sred[wv] = m2;
    __syncthreads();
    float xmax = fmaxf(fmaxf(sred[0], sred[1]), fmaxf(sred[2], sred[3]));
    float xscale = xmax + 1e-5f;
    float inv = 127.f / xscale;
    float osc = (xscale / 127.f) * wscale;

    // ---- quantize + LDS writes: rows 0-4, halo, rows 5-9 (progressive drain) ----
    #pragma unroll
    for (int i = 0; i < 5; ++i) {
        int gh = h0 - 1 + i;
        float vs = ((unsigned)gh < (unsigned)HW) ? inv : 0.f;
        int p0 = i * 34 + pixb;
        xs[lds_h(p0 + 0, c)] = q8(va[i].x * vs);
        xs[lds_h(p0 + 1, c)] = q8(va[i].y * vs);
        xs[lds_h(p0 + 2, c)] = q8(va[i].z * vs);
        xs[lds_h(p0 + 3, c)] = q8(va[i].w * vs);
    }
    #pragma unroll
    for (int it = 0; it < 3; ++it) {
        int e = tid + it * 256;
        if (e < 640) {
            int side = e & 1, cc = (e >> 1) & 31, hp = e >> 6;
            int gh = h0 - 1 + hp;
            int gw = side ? (w0 + TW) : (w0 - 1);
            float vs = ((unsigned)gh < (unsigned)HW && (unsigned)gw < (unsigned)HW)
                           ? inv : 0.f;
            xs[lds_h(hp * 34 + (side ? 33 : 0), cc)] = q8(hv[it] * vs);
        }
    }
    #pragma unroll
    for (int i = 0; i < 5; ++i) {
        int gh = h0 + 4 + i;
        float vs = (gh < HW) ? inv : 0.f;
        int p0 = (5 + i) * 34 + pixb;
        xs[lds_h(p0 + 0, c)] = q8(vb[i].x * vs);
        xs[lds_h(p0 + 1, c)] = q8(vb[i].y * vs);
        xs[lds_h(p0 + 2, c)] = q8(vb[i].z * vs);
        xs[lds_h(p0 + 3, c)] = q8(vb[i].w * vs);
    }
    __syncthreads();

    // ---- MFMA: 9 taps x [2 ri][2 pb][2 kb], one-ahead weight prefetch ----
    int ln = lane & 15, cb = lane >> 4;
    f32x4 acc[2][2][2] = {};
    const short8* wfp = (const short8*)wbuf;
    short8 wa = wfp[lane];
    short8 wb = wfp[64 + lane];
    for (int tap = 0; tap < 9; ++tap) {
        short8 na, nb;
        if (tap < 8) {
            na = wfp[(2 * tap + 2) * 64 + lane];
            nb = wfp[(2 * tap + 3) * 64 + lane];
        }
        int r = tap / 3;
        int s2 = tap - r * 3;
        #pragma unroll
        for (int ri = 0; ri < 2; ++ri) {
            #pragma unroll
            for (int pb = 0; pb < 2; ++pb) {
                int pix = (wv * 2 + ri + r) * 34 + pb * 16 + ln + s2;
                int sw = (pix & 3) ^ ((pix >> 2) & 3);
                const short8 a = *(const short8*)&xs[pix * 32 + (((cb ^ sw) & 3) << 3)];
                acc[ri][pb][0] = __builtin_amdgcn_mfma_f32_16x16x32_bf16(
                    a, wa, acc[ri][pb][0], 0, 0, 0);
                acc[ri][pb][1] = __builtin_amdgcn_mfma_f32_16x16x32_bf16(
                    a, wb, acc[ri][pb][1], 0, 0, 0);
            }
        }
        wa = na;
        wb = nb;
    }

    // ---- epilogue: D row = pixel -> lane holds 4 consecutive px: float4 stores ----
    float* on = out + n * (NCH * PLANE);
    #pragma unroll
    for (int ri = 0; ri < 2; ++ri) {
        int h = h0 + wv * 2 + ri;
        #pragma unroll
        for (int pb = 0; pb < 2; ++pb) {
            int wcol = w0 + pb * 16 + cb * 4;
            #pragma unroll
            for (int kb = 0; kb < 2; ++kb) {
                int k = kb * 16 + ln;
                f32x4 o;
                o[0] = acc[ri][pb][kb][0] * osc;
                o[1] = acc[ri][pb][kb][1] * osc;
                o[2] = acc[ri][pb][kb][2] * osc;
                o[3] = acc[ri][pb][kb][3] * osc;
                *(f32x4*)&on[(k * HW + h) * HW + wcol] = o;
            }
        }
    }
}

extern "C" void kernel_launch(void* const* d_in, const int* in_sizes, int n_in,
                              void* d_out, int out_size, void* d_ws, size_t ws_size,
                              hipStream_t stream)
{
    const float* x = (const float*)d_in[0];
    const float* w = (const float*)d_in[1];
    float* outp = (float*)d_out;
    unsigned* slots = (unsigned*)d_ws;
    float* scal = (float*)((char*)d_ws + 8192);
    unsigned short* wbuf = (unsigned short*)((char*)d_ws + 8448);

    absmax_kernel<<<2048, 256, 0, stream>>>(x, w, slots, scal, wbuf);
    conv_kernel<<<16 * 28 * 7, 256, 0, stream>>>(x, wbuf, slots, scal, outp);
}